// Round 1
// baseline (184.354 us; speedup 1.0000x reference)
//
#include <hip/hip_runtime.h>
#include <math.h>

#define S_DIM 2048
#define L_DIM 4096
#define D_DIM 500
#define NPOI 10000
#define NTIME 48

// ---------------- reductions ----------------
__device__ __forceinline__ float wave_max(float v) {
#pragma unroll
  for (int o = 32; o > 0; o >>= 1) v = fmaxf(v, __shfl_down(v, o, 64));
  return v;
}
__device__ __forceinline__ float wave_sum(float v) {
#pragma unroll
  for (int o = 32; o > 0; o >>= 1) v += __shfl_down(v, o, 64);
  return v;
}

// ---------------- attn_loc: gather + row softmax ----------------
// one block per s-row; 16 gathered values/thread kept in registers
__global__ __launch_bounds__(256) void attn_loc_kernel(
    const int* __restrict__ cur, const int* __restrict__ his,
    const float* __restrict__ poi, float* __restrict__ out) {
  __shared__ float redm[4];
  __shared__ float reds[4];
  const int s = blockIdx.x;
  const int tid = threadIdx.x;
  const float* row = poi + (size_t)cur[s] * NPOI;
  float v[16];
  float lmax = -1e30f;
#pragma unroll
  for (int j = 0; j < 16; ++j) {
    const int l = j * 256 + tid;
    const float d = row[his[l]];
    const float e = (d != 0.0f) ? (1.0f / d) : 1e-6f;
    v[j] = e;
    lmax = fmaxf(lmax, e);
  }
  lmax = wave_max(lmax);
  if ((tid & 63) == 0) redm[tid >> 6] = lmax;
  __syncthreads();
  const float m = fmaxf(fmaxf(redm[0], redm[1]), fmaxf(redm[2], redm[3]));
  float lsum = 0.f;
#pragma unroll
  for (int j = 0; j < 16; ++j) {
    v[j] = __expf(v[j] - m);
    lsum += v[j];
  }
  lsum = wave_sum(lsum);
  if ((tid & 63) == 0) reds[tid >> 6] = lsum;
  __syncthreads();
  const float inv = 1.0f / (reds[0] + reds[1] + reds[2] + reds[3]);
  float* o = out + (size_t)s * L_DIM;
#pragma unroll
  for (int j = 0; j < 16; ++j) o[j * 256 + tid] = v[j] * inv;
}

// ---------------- attn_time: 48x48 probability table ----------------
// single block: histogram his_t, then per cur_t row the softmax over the
// multiset {T[ct][his_t[l]]} collapses to sum_t count[t]*exp(T[ct][t]-m)
__global__ __launch_bounds__(256) void time_table_kernel(
    const int* __restrict__ his_t, const float* __restrict__ T,
    float* __restrict__ P) {
  __shared__ int cnt[NTIME];
  __shared__ float Ts[NTIME * NTIME];
  const int tid = threadIdx.x;
  if (tid < NTIME) cnt[tid] = 0;
  __syncthreads();
  for (int l = tid; l < L_DIM; l += 256) atomicAdd(&cnt[his_t[l]], 1);
  for (int i = tid; i < NTIME * NTIME; i += 256) Ts[i] = T[i];
  __syncthreads();
  if (tid < NTIME) {
    float m = -1e30f;
    for (int t = 0; t < NTIME; ++t) m = fmaxf(m, Ts[tid * NTIME + t]);
    float den = 0.f;
    for (int t = 0; t < NTIME; ++t)
      den += (float)cnt[t] * __expf(Ts[tid * NTIME + t] - m);
    const float inv = 1.0f / den;
    for (int t = 0; t < NTIME; ++t)
      P[tid * NTIME + t] = __expf(Ts[tid * NTIME + t] - m) * inv;
  }
}

// pure table-lookup write of the attn_time plane (write-bound)
__global__ __launch_bounds__(256) void time_out_kernel(
    const int* __restrict__ cur_t, const int* __restrict__ his_t,
    const float* __restrict__ P, float* __restrict__ out) {
  const int i = blockIdx.x * 256 + threadIdx.x;
  const int s = i >> 12;
  const int l = i & (L_DIM - 1);
  out[i] = P[cur_t[s] * NTIME + his_t[l]];
}

// ---------------- attn_user ----------------
// bias[l] = w2 * dot(id_emb[l], soc); one wave per l
__global__ __launch_bounds__(256) void bias_kernel(
    const float* __restrict__ id_emb, const float* __restrict__ soc,
    const float* __restrict__ w2p, float* __restrict__ bias) {
  const int lane = threadIdx.x & 63;
  const int l = blockIdx.x * 4 + (threadIdx.x >> 6);
  const float* r = id_emb + (size_t)l * D_DIM;
  float p = 0.f;
  for (int k = lane; k < D_DIM; k += 64) p += r[k] * soc[k];
  p = wave_sum(p);
  if (lane == 0) bias[l] = w2p[0] * p;
}

// fp32 tiled GEMM: energy = w1 * U(2048x500) . Id(4096x500)^T + bias
// BM=BN=128, BK=20 (500 = 25*20, no K remainder), 256 thr, 8x8 micro
#define BM 128
#define BN 128
#define BK 20
__global__ __launch_bounds__(256) void user_gemm_kernel(
    const float* __restrict__ U, const float* __restrict__ Id,
    const float* __restrict__ bias, const float* __restrict__ w1p,
    float* __restrict__ outE) {
  __shared__ __attribute__((aligned(16))) float As[BK][BM];  // k-major
  __shared__ __attribute__((aligned(16))) float Bs[BK][BN];
  const int tid = threadIdx.x;
  const int tx = tid & 15;   // n
  const int ty = tid >> 4;   // m
  const int bm = blockIdx.y * BM;
  const int bn = blockIdx.x * BN;
  float acc[8][8] = {};
  for (int k0 = 0; k0 < D_DIM; k0 += BK) {
    for (int idx = tid; idx < 640; idx += 256) {
      const int rrow = idx / 5, kq = idx % 5;
      const float4 val = *reinterpret_cast<const float4*>(
          U + (size_t)(bm + rrow) * D_DIM + k0 + kq * 4);
      As[kq * 4 + 0][rrow] = val.x;
      As[kq * 4 + 1][rrow] = val.y;
      As[kq * 4 + 2][rrow] = val.z;
      As[kq * 4 + 3][rrow] = val.w;
    }
    for (int idx = tid; idx < 640; idx += 256) {
      const int rrow = idx / 5, kq = idx % 5;
      const float4 val = *reinterpret_cast<const float4*>(
          Id + (size_t)(bn + rrow) * D_DIM + k0 + kq * 4);
      Bs[kq * 4 + 0][rrow] = val.x;
      Bs[kq * 4 + 1][rrow] = val.y;
      Bs[kq * 4 + 2][rrow] = val.z;
      Bs[kq * 4 + 3][rrow] = val.w;
    }
    __syncthreads();
#pragma unroll
    for (int kk = 0; kk < BK; ++kk) {
      const float4 a0 = *reinterpret_cast<const float4*>(&As[kk][ty * 4]);
      const float4 a1 = *reinterpret_cast<const float4*>(&As[kk][64 + ty * 4]);
      const float4 b0 = *reinterpret_cast<const float4*>(&Bs[kk][tx * 4]);
      const float4 b1 = *reinterpret_cast<const float4*>(&Bs[kk][64 + tx * 4]);
      const float a[8] = {a0.x, a0.y, a0.z, a0.w, a1.x, a1.y, a1.z, a1.w};
      const float b[8] = {b0.x, b0.y, b0.z, b0.w, b1.x, b1.y, b1.z, b1.w};
#pragma unroll
      for (int i = 0; i < 8; ++i)
#pragma unroll
        for (int j = 0; j < 8; ++j) acc[i][j] = fmaf(a[i], b[j], acc[i][j]);
    }
    __syncthreads();
  }
  const float w1 = w1p[0];
  const float4 bb0 = *reinterpret_cast<const float4*>(&bias[bn + tx * 4]);
  const float4 bb1 = *reinterpret_cast<const float4*>(&bias[bn + 64 + tx * 4]);
  const float bj[8] = {bb0.x, bb0.y, bb0.z, bb0.w,
                       bb1.x, bb1.y, bb1.z, bb1.w};
#pragma unroll
  for (int i = 0; i < 8; ++i) {
    const int m = bm + ((i < 4) ? (ty * 4 + i) : (64 + ty * 4 + (i - 4)));
    float4 o0, o1;
    o0.x = fmaf(w1, acc[i][0], bj[0]);
    o0.y = fmaf(w1, acc[i][1], bj[1]);
    o0.z = fmaf(w1, acc[i][2], bj[2]);
    o0.w = fmaf(w1, acc[i][3], bj[3]);
    o1.x = fmaf(w1, acc[i][4], bj[4]);
    o1.y = fmaf(w1, acc[i][5], bj[5]);
    o1.z = fmaf(w1, acc[i][6], bj[6]);
    o1.w = fmaf(w1, acc[i][7], bj[7]);
    *reinterpret_cast<float4*>(outE + (size_t)m * L_DIM + bn + tx * 4) = o0;
    *reinterpret_cast<float4*>(outE + (size_t)m * L_DIM + bn + 64 + tx * 4) = o1;
  }
}

// in-place row softmax of the user plane
__global__ __launch_bounds__(256) void user_softmax_kernel(
    float* __restrict__ outE) {
  __shared__ float redm[4];
  __shared__ float reds[4];
  const int s = blockIdx.x;
  const int tid = threadIdx.x;
  float* row = outE + (size_t)s * L_DIM;
  float4 v[4];
  float lmax = -1e30f;
#pragma unroll
  for (int j = 0; j < 4; ++j) {
    v[j] = *reinterpret_cast<const float4*>(&row[(j * 256 + tid) * 4]);
    lmax = fmaxf(lmax, fmaxf(fmaxf(v[j].x, v[j].y), fmaxf(v[j].z, v[j].w)));
  }
  lmax = wave_max(lmax);
  if ((tid & 63) == 0) redm[tid >> 6] = lmax;
  __syncthreads();
  const float m = fmaxf(fmaxf(redm[0], redm[1]), fmaxf(redm[2], redm[3]));
  float lsum = 0.f;
#pragma unroll
  for (int j = 0; j < 4; ++j) {
    v[j].x = __expf(v[j].x - m);
    v[j].y = __expf(v[j].y - m);
    v[j].z = __expf(v[j].z - m);
    v[j].w = __expf(v[j].w - m);
    lsum += v[j].x + v[j].y + v[j].z + v[j].w;
  }
  lsum = wave_sum(lsum);
  if ((tid & 63) == 0) reds[tid >> 6] = lsum;
  __syncthreads();
  const float inv = 1.0f / (reds[0] + reds[1] + reds[2] + reds[3]);
#pragma unroll
  for (int j = 0; j < 4; ++j) {
    v[j].x *= inv;
    v[j].y *= inv;
    v[j].z *= inv;
    v[j].w *= inv;
    *reinterpret_cast<float4*>(&row[(j * 256 + tid) * 4]) = v[j];
  }
}

extern "C" void kernel_launch(void* const* d_in, const int* in_sizes, int n_in,
                              void* d_out, int out_size, void* d_ws,
                              size_t ws_size, hipStream_t stream) {
  const int* his = (const int*)d_in[0];
  const int* cur = (const int*)d_in[1];
  const int* his_t = (const int*)d_in[2];
  const int* cur_t = (const int*)d_in[3];
  const float* poi = (const float*)d_in[4];
  const float* tsim = (const float*)d_in[5];
  const float* uemb = (const float*)d_in[6];
  const float* idemb = (const float*)d_in[7];
  const float* soc = (const float*)d_in[8];
  const float* w1 = (const float*)d_in[9];
  const float* w2 = (const float*)d_in[10];

  float* out = (float*)d_out;
  float* out_loc = out;
  float* out_time = out + (size_t)S_DIM * L_DIM;
  float* out_user = out + 2 * (size_t)S_DIM * L_DIM;

  float* bias = (float*)d_ws;        // 4096 floats
  float* P = (float*)d_ws + L_DIM;   // 48*48 floats

  hipLaunchKernelGGL(time_table_kernel, dim3(1), dim3(256), 0, stream, his_t,
                     tsim, P);
  hipLaunchKernelGGL(time_out_kernel, dim3((S_DIM * L_DIM) / 256), dim3(256),
                     0, stream, cur_t, his_t, P, out_time);
  hipLaunchKernelGGL(bias_kernel, dim3(L_DIM / 4), dim3(256), 0, stream, idemb,
                     soc, w2, bias);
  hipLaunchKernelGGL(user_gemm_kernel, dim3(L_DIM / BN, S_DIM / BM), dim3(256),
                     0, stream, uemb, idemb, bias, w1, out_user);
  hipLaunchKernelGGL(user_softmax_kernel, dim3(S_DIM), dim3(256), 0, stream,
                     out_user);
  hipLaunchKernelGGL(attn_loc_kernel, dim3(S_DIM), dim3(256), 0, stream, cur,
                     his, poi, out_loc);
}

// Round 2
// 114.936 us; speedup vs baseline: 1.6040x; 1.6040x over previous
//
#include <hip/hip_runtime.h>
#include <math.h>

#define S_DIM 2048
#define L_DIM 4096
#define D_DIM 500
#define KPAD 512
#define NPOI 10000
#define NTIME 48

typedef __attribute__((ext_vector_type(8))) short short8;
typedef __attribute__((ext_vector_type(4))) float f32x4;

// ---------------- helpers ----------------
__device__ __forceinline__ float wave_max(float v) {
#pragma unroll
  for (int o = 32; o > 0; o >>= 1) v = fmaxf(v, __shfl_down(v, o, 64));
  return v;
}
__device__ __forceinline__ float wave_sum(float v) {
#pragma unroll
  for (int o = 32; o > 0; o >>= 1) v += __shfl_down(v, o, 64);
  return v;
}
__device__ __forceinline__ short f2bf(float x) {  // RNE f32 -> bf16 bits
  union { float f; unsigned u; } v;
  v.f = x;
  const unsigned r = v.u + 0x7fffu + ((v.u >> 16) & 1u);
  return (short)(r >> 16);
}
__device__ __forceinline__ float bf2f(short h) {
  union { unsigned u; float f; } v;
  v.u = ((unsigned)(unsigned short)h) << 16;
  return v.f;
}

// ---------------- attn_loc: gather + row softmax ----------------
__global__ __launch_bounds__(256) void attn_loc_kernel(
    const int* __restrict__ cur, const int* __restrict__ his,
    const float* __restrict__ poi, float* __restrict__ out) {
  __shared__ float redm[4];
  __shared__ float reds[4];
  const int s = blockIdx.x;
  const int tid = threadIdx.x;
  const float* row = poi + (size_t)cur[s] * NPOI;
  float v[16];
  float lmax = -1e30f;
#pragma unroll
  for (int j = 0; j < 16; ++j) {
    const int l = j * 256 + tid;
    const float d = row[his[l]];
    const float e = (d != 0.0f) ? (1.0f / d) : 1e-6f;
    v[j] = e;
    lmax = fmaxf(lmax, e);
  }
  lmax = wave_max(lmax);
  if ((tid & 63) == 0) redm[tid >> 6] = lmax;
  __syncthreads();
  const float m = fmaxf(fmaxf(redm[0], redm[1]), fmaxf(redm[2], redm[3]));
  float lsum = 0.f;
#pragma unroll
  for (int j = 0; j < 16; ++j) {
    v[j] = __expf(v[j] - m);
    lsum += v[j];
  }
  lsum = wave_sum(lsum);
  if ((tid & 63) == 0) reds[tid >> 6] = lsum;
  __syncthreads();
  const float inv = 1.0f / (reds[0] + reds[1] + reds[2] + reds[3]);
  float* o = out + (size_t)s * L_DIM;
#pragma unroll
  for (int j = 0; j < 16; ++j) o[j * 256 + tid] = v[j] * inv;
}

// ---------------- attn_time ----------------
__global__ __launch_bounds__(256) void time_table_kernel(
    const int* __restrict__ his_t, const float* __restrict__ T,
    float* __restrict__ P) {
  __shared__ int cnt[NTIME];
  __shared__ float Ts[NTIME * NTIME];
  const int tid = threadIdx.x;
  if (tid < NTIME) cnt[tid] = 0;
  __syncthreads();
  for (int l = tid; l < L_DIM; l += 256) atomicAdd(&cnt[his_t[l]], 1);
  for (int i = tid; i < NTIME * NTIME; i += 256) Ts[i] = T[i];
  __syncthreads();
  if (tid < NTIME) {
    float m = -1e30f;
    for (int t = 0; t < NTIME; ++t) m = fmaxf(m, Ts[tid * NTIME + t]);
    float den = 0.f;
    for (int t = 0; t < NTIME; ++t)
      den += (float)cnt[t] * __expf(Ts[tid * NTIME + t] - m);
    const float inv = 1.0f / den;
    for (int t = 0; t < NTIME; ++t)
      P[tid * NTIME + t] = __expf(Ts[tid * NTIME + t] - m) * inv;
  }
}

__global__ __launch_bounds__(256) void time_out_kernel(
    const int* __restrict__ cur_t, const int* __restrict__ his_t,
    const float* __restrict__ P, float* __restrict__ out) {
  const int i = blockIdx.x * 256 + threadIdx.x;
  const int s = i >> 12;
  const int l = i & (L_DIM - 1);
  out[i] = P[cur_t[s] * NTIME + his_t[l]];
}

// ---------------- attn_user ----------------
// bias[l] = w2 * dot(id_emb[l], soc)
__global__ __launch_bounds__(256) void bias_kernel(
    const float* __restrict__ id_emb, const float* __restrict__ soc,
    const float* __restrict__ w2p, float* __restrict__ bias) {
  const int lane = threadIdx.x & 63;
  const int l = blockIdx.x * 4 + (threadIdx.x >> 6);
  const float* r = id_emb + (size_t)l * D_DIM;
  float p = 0.f;
  for (int k = lane; k < D_DIM; k += 64) p += r[k] * soc[k];
  p = wave_sum(p);
  if (lane == 0) bias[l] = w2p[0] * p;
}

// split f32 operands into hi/lo bf16 planes, K padded to 512.
// rows 0..2047 = w1*user_emb, rows 2048..6143 = id_emb
__global__ __launch_bounds__(256) void split_kernel(
    const float* __restrict__ U, const float* __restrict__ Id,
    const float* __restrict__ w1p, short* __restrict__ hi,
    short* __restrict__ lo) {
  const int chunk = blockIdx.x * 256 + threadIdx.x;  // 8 k-elems per chunk
  const int row = chunk >> 6;                        // KPAD/8 = 64 chunks/row
  const int ko = (chunk & 63) * 8;
  const float scale = (row < S_DIM) ? w1p[0] : 1.0f;
  const float* src = (row < S_DIM) ? (U + (size_t)row * D_DIM)
                                   : (Id + (size_t)(row - S_DIM) * D_DIM);
  short h[8], l[8];
#pragma unroll
  for (int j = 0; j < 8; ++j) {
    const int k = ko + j;
    const float x = (k < D_DIM) ? scale * src[k] : 0.0f;
    const short hb = f2bf(x);
    h[j] = hb;
    l[j] = f2bf(x - bf2f(hb));
  }
  *reinterpret_cast<int4*>(hi + (size_t)row * KPAD + ko) =
      *reinterpret_cast<const int4*>(h);
  *reinterpret_cast<int4*>(lo + (size_t)row * KPAD + ko) =
      *reinterpret_cast<const int4*>(l);
}

// split-bf16 MFMA GEMM: E = (w1*U) . Id^T + bias  via hi*hi + hi*lo + lo*hi
// 128x128 tile, BK=32, 4 waves (2x2), per-wave 64x64 = 4x4 frags of 16x16x32
#define LDT 56  // LDS row pitch in shorts (112 B = 7*16B: aligned, 2-way banks)
__global__ __launch_bounds__(256) void user_gemm_mfma(
    const short* __restrict__ hi, const short* __restrict__ lo,
    const float* __restrict__ bias, float* __restrict__ outE) {
  __shared__ short As_hi[128][LDT];
  __shared__ short As_lo[128][LDT];
  __shared__ short Bs_hi[128][LDT];
  __shared__ short Bs_lo[128][LDT];
  const int tid = threadIdx.x;
  const int lane = tid & 63;
  const int wid = tid >> 6;
  const int wm = (wid >> 1) * 64;
  const int wn = (wid & 1) * 64;
  const int fr = lane & 15;
  const int kq = (lane >> 4) * 8;
  const int bm = blockIdx.y * 128;
  const int bn = blockIdx.x * 128;

  f32x4 acc[4][4] = {};

  for (int kt = 0; kt < KPAD / 32; ++kt) {
    const int k0 = kt * 32;
#pragma unroll
    for (int cc = 0; cc < 2; ++cc) {
      const int c = tid + cc * 256;  // 0..511
      const int row = c >> 2;        // 0..127
      const int ko = (c & 3) * 8;    // 0,8,16,24
      const size_t ga = (size_t)(bm + row) * KPAD + k0 + ko;
      const size_t gb = (size_t)(S_DIM + bn + row) * KPAD + k0 + ko;
      *reinterpret_cast<short8*>(&As_hi[row][ko]) =
          *reinterpret_cast<const short8*>(hi + ga);
      *reinterpret_cast<short8*>(&As_lo[row][ko]) =
          *reinterpret_cast<const short8*>(lo + ga);
      *reinterpret_cast<short8*>(&Bs_hi[row][ko]) =
          *reinterpret_cast<const short8*>(hi + gb);
      *reinterpret_cast<short8*>(&Bs_lo[row][ko]) =
          *reinterpret_cast<const short8*>(lo + gb);
    }
    __syncthreads();
    short8 ah[4], al[4], bh[4], bl[4];
#pragma unroll
    for (int t = 0; t < 4; ++t) {
      ah[t] = *reinterpret_cast<const short8*>(&As_hi[wm + t * 16 + fr][kq]);
      al[t] = *reinterpret_cast<const short8*>(&As_lo[wm + t * 16 + fr][kq]);
      bh[t] = *reinterpret_cast<const short8*>(&Bs_hi[wn + t * 16 + fr][kq]);
      bl[t] = *reinterpret_cast<const short8*>(&Bs_lo[wn + t * 16 + fr][kq]);
    }
#pragma unroll
    for (int i = 0; i < 4; ++i)
#pragma unroll
      for (int j = 0; j < 4; ++j) {
        acc[i][j] =
            __builtin_amdgcn_mfma_f32_16x16x32_bf16(ah[i], bh[j], acc[i][j], 0, 0, 0);
        acc[i][j] =
            __builtin_amdgcn_mfma_f32_16x16x32_bf16(ah[i], bl[j], acc[i][j], 0, 0, 0);
        acc[i][j] =
            __builtin_amdgcn_mfma_f32_16x16x32_bf16(al[i], bh[j], acc[i][j], 0, 0, 0);
      }
    __syncthreads();
  }

  // epilogue: C/D layout col = lane&15, row = (lane>>4)*4 + reg (m89)
  const int rg = (lane >> 4) * 4;
  float bj[4];
#pragma unroll
  for (int j = 0; j < 4; ++j) bj[j] = bias[bn + wn + j * 16 + fr];
#pragma unroll
  for (int i = 0; i < 4; ++i)
#pragma unroll
    for (int j = 0; j < 4; ++j) {
      const int col = bn + wn + j * 16 + fr;
#pragma unroll
      for (int r = 0; r < 4; ++r) {
        const int rowm = bm + wm + i * 16 + rg + r;
        outE[(size_t)rowm * L_DIM + col] = acc[i][j][r] + bj[j];
      }
    }
}

// in-place row softmax of the user plane
__global__ __launch_bounds__(256) void user_softmax_kernel(
    float* __restrict__ outE) {
  __shared__ float redm[4];
  __shared__ float reds[4];
  const int s = blockIdx.x;
  const int tid = threadIdx.x;
  float* row = outE + (size_t)s * L_DIM;
  float4 v[4];
  float lmax = -1e30f;
#pragma unroll
  for (int j = 0; j < 4; ++j) {
    v[j] = *reinterpret_cast<const float4*>(&row[(j * 256 + tid) * 4]);
    lmax = fmaxf(lmax, fmaxf(fmaxf(v[j].x, v[j].y), fmaxf(v[j].z, v[j].w)));
  }
  lmax = wave_max(lmax);
  if ((tid & 63) == 0) redm[tid >> 6] = lmax;
  __syncthreads();
  const float m = fmaxf(fmaxf(redm[0], redm[1]), fmaxf(redm[2], redm[3]));
  float lsum = 0.f;
#pragma unroll
  for (int j = 0; j < 4; ++j) {
    v[j].x = __expf(v[j].x - m);
    v[j].y = __expf(v[j].y - m);
    v[j].z = __expf(v[j].z - m);
    v[j].w = __expf(v[j].w - m);
    lsum += v[j].x + v[j].y + v[j].z + v[j].w;
  }
  lsum = wave_sum(lsum);
  if ((tid & 63) == 0) reds[tid >> 6] = lsum;
  __syncthreads();
  const float inv = 1.0f / (reds[0] + reds[1] + reds[2] + reds[3]);
#pragma unroll
  for (int j = 0; j < 4; ++j) {
    v[j].x *= inv;
    v[j].y *= inv;
    v[j].z *= inv;
    v[j].w *= inv;
    *reinterpret_cast<float4*>(&row[(j * 256 + tid) * 4]) = v[j];
  }
}

extern "C" void kernel_launch(void* const* d_in, const int* in_sizes, int n_in,
                              void* d_out, int out_size, void* d_ws,
                              size_t ws_size, hipStream_t stream) {
  const int* his = (const int*)d_in[0];
  const int* cur = (const int*)d_in[1];
  const int* his_t = (const int*)d_in[2];
  const int* cur_t = (const int*)d_in[3];
  const float* poi = (const float*)d_in[4];
  const float* tsim = (const float*)d_in[5];
  const float* uemb = (const float*)d_in[6];
  const float* idemb = (const float*)d_in[7];
  const float* soc = (const float*)d_in[8];
  const float* w1 = (const float*)d_in[9];
  const float* w2 = (const float*)d_in[10];

  float* out = (float*)d_out;
  float* out_loc = out;
  float* out_time = out + (size_t)S_DIM * L_DIM;
  float* out_user = out + 2 * (size_t)S_DIM * L_DIM;

  // scratch layout: hi/lo bf16 split planes (12.6 MB) + bias + P.
  // If ws is too small, stash hi/lo in the attn_loc output plane (33.5 MB),
  // which is overwritten by attn_loc_kernel at the very end.
  const size_t split_elems = (size_t)(S_DIM + L_DIM) * KPAD;  // 3.1M shorts ea
  const size_t split_bytes = split_elems * 2 * 2;
  short* hi;
  short* lo;
  float* bias;
  float* P;
  if (ws_size >= split_bytes + 32768) {
    hi = (short*)d_ws;
    lo = hi + split_elems;
    bias = (float*)((char*)d_ws + split_bytes);
    P = bias + L_DIM;
  } else {
    hi = (short*)out_loc;
    lo = hi + split_elems;
    bias = (float*)d_ws;
    P = bias + L_DIM;
  }

  hipLaunchKernelGGL(split_kernel, dim3((S_DIM + L_DIM) * (KPAD / 8) / 256),
                     dim3(256), 0, stream, uemb, idemb, w1, hi, lo);
  hipLaunchKernelGGL(bias_kernel, dim3(L_DIM / 4), dim3(256), 0, stream, idemb,
                     soc, w2, bias);
  hipLaunchKernelGGL(user_gemm_mfma, dim3(L_DIM / 128, S_DIM / 128), dim3(256),
                     0, stream, hi, lo, bias, out_user);
  hipLaunchKernelGGL(user_softmax_kernel, dim3(S_DIM), dim3(256), 0, stream,
                     out_user);
  hipLaunchKernelGGL(time_table_kernel, dim3(1), dim3(256), 0, stream, his_t,
                     tsim, P);
  hipLaunchKernelGGL(time_out_kernel, dim3((S_DIM * L_DIM) / 256), dim3(256),
                     0, stream, cur_t, his_t, P, out_time);
  hipLaunchKernelGGL(attn_loc_kernel, dim3(S_DIM), dim3(256), 0, stream, cur,
                     his, poi, out_loc);
}

// Round 3
// 112.394 us; speedup vs baseline: 1.6403x; 1.0226x over previous
//
#include <hip/hip_runtime.h>
#include <math.h>

#define S_DIM 2048
#define L_DIM 4096
#define D_DIM 500
#define KPAD 512
#define NPOI 10000
#define NTIME 48

typedef __attribute__((ext_vector_type(8))) short short8;
typedef __attribute__((ext_vector_type(4))) float f32x4;
typedef __attribute__((ext_vector_type(16))) float f32x16;

// ---------------- helpers ----------------
__device__ __forceinline__ float wave_max(float v) {
#pragma unroll
  for (int o = 32; o > 0; o >>= 1) v = fmaxf(v, __shfl_down(v, o, 64));
  return v;
}
__device__ __forceinline__ float wave_sum(float v) {
#pragma unroll
  for (int o = 32; o > 0; o >>= 1) v += __shfl_down(v, o, 64);
  return v;
}
__device__ __forceinline__ short f2bf(float x) {  // RNE f32 -> bf16 bits
  union { float f; unsigned u; } v;
  v.f = x;
  const unsigned r = v.u + 0x7fffu + ((v.u >> 16) & 1u);
  return (short)(r >> 16);
}
__device__ __forceinline__ float bf2f(short h) {
  union { unsigned u; float f; } v;
  v.u = ((unsigned)(unsigned short)h) << 16;
  return v.f;
}

// ---------------- attn_loc: gather + row softmax ----------------
__global__ __launch_bounds__(256) void attn_loc_kernel(
    const int* __restrict__ cur, const int* __restrict__ his,
    const float* __restrict__ poi, float* __restrict__ out) {
  __shared__ float redm[4];
  __shared__ float reds[4];
  const int s = blockIdx.x;
  const int tid = threadIdx.x;
  const float* row = poi + (size_t)cur[s] * NPOI;
  float v[16];
  float lmax = -1e30f;
#pragma unroll
  for (int j = 0; j < 16; ++j) {
    const int l = j * 256 + tid;
    const float d = row[his[l]];
    const float e = (d != 0.0f) ? (1.0f / d) : 1e-6f;
    v[j] = e;
    lmax = fmaxf(lmax, e);
  }
  lmax = wave_max(lmax);
  if ((tid & 63) == 0) redm[tid >> 6] = lmax;
  __syncthreads();
  const float m = fmaxf(fmaxf(redm[0], redm[1]), fmaxf(redm[2], redm[3]));
  float lsum = 0.f;
#pragma unroll
  for (int j = 0; j < 16; ++j) {
    v[j] = __expf(v[j] - m);
    lsum += v[j];
  }
  lsum = wave_sum(lsum);
  if ((tid & 63) == 0) reds[tid >> 6] = lsum;
  __syncthreads();
  const float inv = 1.0f / (reds[0] + reds[1] + reds[2] + reds[3]);
  float* o = out + (size_t)s * L_DIM;
#pragma unroll
  for (int j = 0; j < 16; ++j) o[j * 256 + tid] = v[j] * inv;
}

// ---------------- attn_time ----------------
__global__ __launch_bounds__(256) void time_table_kernel(
    const int* __restrict__ his_t, const float* __restrict__ T,
    float* __restrict__ P) {
  __shared__ int cnt[NTIME];
  __shared__ float Ts[NTIME * NTIME];
  const int tid = threadIdx.x;
  if (tid < NTIME) cnt[tid] = 0;
  __syncthreads();
  for (int l = tid; l < L_DIM; l += 256) atomicAdd(&cnt[his_t[l]], 1);
  for (int i = tid; i < NTIME * NTIME; i += 256) Ts[i] = T[i];
  __syncthreads();
  if (tid < NTIME) {
    float m = -1e30f;
    for (int t = 0; t < NTIME; ++t) m = fmaxf(m, Ts[tid * NTIME + t]);
    float den = 0.f;
    for (int t = 0; t < NTIME; ++t)
      den += (float)cnt[t] * __expf(Ts[tid * NTIME + t] - m);
    const float inv = 1.0f / den;
    for (int t = 0; t < NTIME; ++t)
      P[tid * NTIME + t] = __expf(Ts[tid * NTIME + t] - m) * inv;
  }
}

__global__ __launch_bounds__(256) void time_out_kernel(
    const int* __restrict__ cur_t, const int* __restrict__ his_t,
    const float* __restrict__ P, float* __restrict__ out) {
  const int i = blockIdx.x * 256 + threadIdx.x;
  const int s = i >> 12;
  const int l = i & (L_DIM - 1);
  out[i] = P[cur_t[s] * NTIME + his_t[l]];
}

// ---------------- split: f32 -> tiled+swizzled hi/lo bf16 planes ----------
// Unified 6144-row space: rows 0..2047 = w1*user_emb, 2048..6143 = id_emb.
// Plane layout: tile (rb, ks, comp) of 8KB; rb=row>>7 in [0,48), ks in [0,16),
// comp 0=hi 1=lo. Within tile, element (rin, quad kq, e):
//   byte off = rin*64 + ((kq ^ ((rin>>1)&3)) * 16) + e*2   (bank XOR baked in)
// Also fuses bias[l] = w2 * dot(id_emb[l], soc): one wave == one row here.
__global__ __launch_bounds__(256) void split_kernel(
    const float* __restrict__ U, const float* __restrict__ Id,
    const float* __restrict__ w1p, const float* __restrict__ soc,
    const float* __restrict__ w2p, short* __restrict__ planes,
    float* __restrict__ bias) {
  const int chunk = blockIdx.x * 256 + threadIdx.x;
  const int row = chunk >> 6;  // 0..6143 (64 16B-chunks per row)
  const int lq = chunk & 63;   // k = lq*8 .. lq*8+7
  const bool isA = row < S_DIM;
  const float scale = isA ? w1p[0] : 1.0f;
  const float* src = isA ? (U + (size_t)row * D_DIM)
                         : (Id + (size_t)(row - S_DIM) * D_DIM);
  const int k0 = lq * 8;
  float dot = 0.f;
  short h[8], l[8];
#pragma unroll
  for (int e = 0; e < 8; ++e) {
    const int k = k0 + e;
    const float v = (k < D_DIM) ? src[k] : 0.0f;
    if (!isA && k < D_DIM) dot += v * soc[k];
    const float x = scale * v;
    const short hb = f2bf(x);
    h[e] = hb;
    l[e] = f2bf(x - bf2f(hb));
  }
  const int rb = row >> 7, rin = row & 127;
  const int ks = lq >> 2, kq = lq & 3;
  const int off = rin * 64 + ((kq ^ ((rin >> 1) & 3)) * 16);
  char* base = (char*)planes + ((size_t)(rb * 16 + ks) * 2) * 8192;
  *reinterpret_cast<int4*>(base + off) = *reinterpret_cast<const int4*>(h);
  *reinterpret_cast<int4*>(base + 8192 + off) =
      *reinterpret_cast<const int4*>(l);
  if (!isA) {
    const float d = wave_sum(dot);
    if ((threadIdx.x & 63) == 0) bias[row - S_DIM] = w2p[0] * d;
  }
}

// ---------------- split-bf16 MFMA GEMM (m97 structure) ----------------
// E = (w1*U).Id^T + bias via hi*hi + hi*lo + lo*hi, mfma_f32_32x32x16_bf16.
// 128x128 tile, BK=32, 4 waves (2x2, 64x64 each = 2x2 frags of 32x32).
// Staging: global_load_lds width=16 from the pre-tiled planes (linear copy).
__global__ __launch_bounds__(256, 2) void user_gemm_mfma(
    const short* __restrict__ planes, const float* __restrict__ bias,
    float* __restrict__ outE) {
  __shared__ __attribute__((aligned(1024))) char lds[32768];
  // LDS: Ahi @0, Alo @8192, Bhi @16384, Blo @24576
  const int tid = threadIdx.x;
  const int lane = tid & 63;
  const int wid = tid >> 6;
  const int wm = (wid >> 1) * 64;
  const int wn = (wid & 1) * 64;
  const int bm = blockIdx.y * 128;
  const int bn = blockIdx.x * 128;
  const int arb = blockIdx.y;         // A rowblock
  const int brb = 16 + blockIdx.x;    // B rowblock (B rows start at 2048)
  const char* gA = (const char*)planes + (size_t)arb * 16 * 2 * 8192;
  const char* gB = (const char*)planes + (size_t)brb * 16 * 2 * 8192;

  const int r32 = lane & 31;
  const int khl = lane >> 5;  // k-half within fragment

  f32x16 acc[2][2] = {};

  for (int ks = 0; ks < KPAD / 32; ++ks) {
    const char* tA = gA + (size_t)ks * 16384;
    const char* tB = gB + (size_t)ks * 16384;
#pragma unroll
    for (int q = 0; q < 4; ++q) {
      const int c = (q * 256 + tid) * 16;  // 0..16368
      __builtin_amdgcn_global_load_lds(
          (const __attribute__((address_space(1))) unsigned int*)(tA + c),
          (__attribute__((address_space(3))) unsigned int*)(lds + c), 16, 0, 0);
      __builtin_amdgcn_global_load_lds(
          (const __attribute__((address_space(1))) unsigned int*)(tB + c),
          (__attribute__((address_space(3))) unsigned int*)(lds + 16384 + c),
          16, 0, 0);
    }
    __syncthreads();
#pragma unroll
    for (int kf = 0; kf < 2; ++kf) {
      short8 ah[2], al[2], bh[2], bl[2];
#pragma unroll
      for (int i = 0; i < 2; ++i) {
        const int ra = wm + i * 32 + r32;
        const int rb_ = wn + i * 32 + r32;
        const int ga = ((kf * 2 + khl) ^ ((ra >> 1) & 3)) * 16;
        const int gb = ((kf * 2 + khl) ^ ((rb_ >> 1) & 3)) * 16;
        ah[i] = *reinterpret_cast<const short8*>(lds + ra * 64 + ga);
        al[i] = *reinterpret_cast<const short8*>(lds + 8192 + ra * 64 + ga);
        bh[i] = *reinterpret_cast<const short8*>(lds + 16384 + rb_ * 64 + gb);
        bl[i] = *reinterpret_cast<const short8*>(lds + 24576 + rb_ * 64 + gb);
      }
#pragma unroll
      for (int i = 0; i < 2; ++i)
#pragma unroll
        for (int j = 0; j < 2; ++j) {
          acc[i][j] = __builtin_amdgcn_mfma_f32_32x32x16_bf16(
              ah[i], bh[j], acc[i][j], 0, 0, 0);
          acc[i][j] = __builtin_amdgcn_mfma_f32_32x32x16_bf16(
              ah[i], bl[j], acc[i][j], 0, 0, 0);
          acc[i][j] = __builtin_amdgcn_mfma_f32_32x32x16_bf16(
              al[i], bh[j], acc[i][j], 0, 0, 0);
        }
    }
    __syncthreads();
  }

  // C/D layout (m74/m101): col=lane&31, row=(reg&3)+8*(reg>>2)+4*(lane>>5)
#pragma unroll
  for (int j = 0; j < 2; ++j) {
    const int col = bn + wn + j * 32 + r32;
    const float bj = bias[col];
#pragma unroll
    for (int i = 0; i < 2; ++i) {
      const int rbase = bm + wm + i * 32 + 4 * khl;
#pragma unroll
      for (int reg = 0; reg < 16; ++reg) {
        const int rowm = rbase + (reg & 3) + 8 * (reg >> 2);
        outE[(size_t)rowm * L_DIM + col] = acc[i][j][reg] + bj;
      }
    }
  }
}

// in-place row softmax of the user plane
__global__ __launch_bounds__(256) void user_softmax_kernel(
    float* __restrict__ outE) {
  __shared__ float redm[4];
  __shared__ float reds[4];
  const int s = blockIdx.x;
  const int tid = threadIdx.x;
  float* row = outE + (size_t)s * L_DIM;
  float4 v[4];
  float lmax = -1e30f;
#pragma unroll
  for (int j = 0; j < 4; ++j) {
    v[j] = *reinterpret_cast<const float4*>(&row[(j * 256 + tid) * 4]);
    lmax = fmaxf(lmax, fmaxf(fmaxf(v[j].x, v[j].y), fmaxf(v[j].z, v[j].w)));
  }
  lmax = wave_max(lmax);
  if ((tid & 63) == 0) redm[tid >> 6] = lmax;
  __syncthreads();
  const float m = fmaxf(fmaxf(redm[0], redm[1]), fmaxf(redm[2], redm[3]));
  float lsum = 0.f;
#pragma unroll
  for (int j = 0; j < 4; ++j) {
    v[j].x = __expf(v[j].x - m);
    v[j].y = __expf(v[j].y - m);
    v[j].z = __expf(v[j].z - m);
    v[j].w = __expf(v[j].w - m);
    lsum += v[j].x + v[j].y + v[j].z + v[j].w;
  }
  lsum = wave_sum(lsum);
  if ((tid & 63) == 0) reds[tid >> 6] = lsum;
  __syncthreads();
  const float inv = 1.0f / (reds[0] + reds[1] + reds[2] + reds[3]);
#pragma unroll
  for (int j = 0; j < 4; ++j) {
    v[j].x *= inv;
    v[j].y *= inv;
    v[j].z *= inv;
    v[j].w *= inv;
    *reinterpret_cast<float4*>(&row[(j * 256 + tid) * 4]) = v[j];
  }
}

extern "C" void kernel_launch(void* const* d_in, const int* in_sizes, int n_in,
                              void* d_out, int out_size, void* d_ws,
                              size_t ws_size, hipStream_t stream) {
  const int* his = (const int*)d_in[0];
  const int* cur = (const int*)d_in[1];
  const int* his_t = (const int*)d_in[2];
  const int* cur_t = (const int*)d_in[3];
  const float* poi = (const float*)d_in[4];
  const float* tsim = (const float*)d_in[5];
  const float* uemb = (const float*)d_in[6];
  const float* idemb = (const float*)d_in[7];
  const float* soc = (const float*)d_in[8];
  const float* w1 = (const float*)d_in[9];
  const float* w2 = (const float*)d_in[10];

  float* out = (float*)d_out;
  float* out_loc = out;
  float* out_time = out + (size_t)S_DIM * L_DIM;
  float* out_user = out + 2 * (size_t)S_DIM * L_DIM;

  // planes: 48 rowblocks x 16 ksteps x 2 comps x 8KB = 12.58 MB
  const size_t plane_bytes = (size_t)48 * 16 * 2 * 8192;
  short* planes;
  float* bias;
  float* P;
  if (ws_size >= plane_bytes + 32768) {
    planes = (short*)d_ws;
    bias = (float*)((char*)d_ws + plane_bytes);
    P = bias + L_DIM;
  } else {
    // fallback: stash planes in the attn_loc output plane (33.5 MB),
    // which is only written by attn_loc_kernel at the very end.
    planes = (short*)out_loc;
    bias = (float*)d_ws;
    P = bias + L_DIM;
  }

  hipLaunchKernelGGL(split_kernel, dim3((S_DIM + L_DIM) * 64 / 256), dim3(256),
                     0, stream, uemb, idemb, w1, soc, w2, planes, bias);
  hipLaunchKernelGGL(user_gemm_mfma, dim3(L_DIM / 128, S_DIM / 128), dim3(256),
                     0, stream, planes, bias, out_user);
  hipLaunchKernelGGL(user_softmax_kernel, dim3(S_DIM), dim3(256), 0, stream,
                     out_user);
  hipLaunchKernelGGL(time_table_kernel, dim3(1), dim3(256), 0, stream, his_t,
                     tsim, P);
  hipLaunchKernelGGL(time_out_kernel, dim3((S_DIM * L_DIM) / 256), dim3(256),
                     0, stream, cur_t, his_t, P, out_time);
  hipLaunchKernelGGL(attn_loc_kernel, dim3(S_DIM), dim3(256), 0, stream, cur,
                     his, poi, out_loc);
}

// Round 4
// 104.076 us; speedup vs baseline: 1.7713x; 1.0799x over previous
//
#include <hip/hip_runtime.h>
#include <math.h>

#define S_DIM 2048
#define L_DIM 4096
#define D_DIM 500
#define KPAD 512
#define NPOI 10000
#define NTIME 48

typedef __attribute__((ext_vector_type(8))) short short8;
typedef __attribute__((ext_vector_type(4))) float f32x4;
typedef __attribute__((ext_vector_type(16))) float f32x16;

// ---------------- helpers ----------------
__device__ __forceinline__ float wave_max(float v) {
#pragma unroll
  for (int o = 32; o > 0; o >>= 1) v = fmaxf(v, __shfl_down(v, o, 64));
  return v;
}
__device__ __forceinline__ float wave_sum(float v) {
#pragma unroll
  for (int o = 32; o > 0; o >>= 1) v += __shfl_down(v, o, 64);
  return v;
}
__device__ __forceinline__ short f2bf(float x) {  // RNE f32 -> bf16 bits
  union { float f; unsigned u; } v;
  v.f = x;
  const unsigned r = v.u + 0x7fffu + ((v.u >> 16) & 1u);
  return (short)(r >> 16);
}
__device__ __forceinline__ float bf2f(short h) {
  union { unsigned u; float f; } v;
  v.u = ((unsigned)(unsigned short)h) << 16;
  return v.f;
}

// ---------------- attn_loc: LDS-staged row + LDS gather + softmax --------
// The poi row gather was TA-serialized (~61 lines per wave-gather). Stage the
// 40KB row into LDS coalesced first; random LDS gather is ~2 lanes/bank = free.
__global__ __launch_bounds__(256) void attn_loc_kernel(
    const int* __restrict__ cur, const int* __restrict__ his,
    const float* __restrict__ poi, float* __restrict__ out) {
  __shared__ float rowbuf[NPOI];  // 40000 B
  __shared__ float redm[4];
  __shared__ float reds[4];
  const int s = blockIdx.x;
  const int tid = threadIdx.x;
  const float* row = poi + (size_t)cur[s] * NPOI;  // 40000B-aligned
  for (int i = tid; i < NPOI / 4; i += 256)
    *reinterpret_cast<float4*>(&rowbuf[i * 4]) =
        *reinterpret_cast<const float4*>(row + i * 4);
  __syncthreads();
  float v[16];
  float lmax = -1e30f;
#pragma unroll
  for (int j = 0; j < 16; ++j) {
    const int l = j * 256 + tid;
    const float d = rowbuf[his[l]];
    const float e = (d != 0.0f) ? (1.0f / d) : 1e-6f;
    v[j] = e;
    lmax = fmaxf(lmax, e);
  }
  lmax = wave_max(lmax);
  if ((tid & 63) == 0) redm[tid >> 6] = lmax;
  __syncthreads();
  const float m = fmaxf(fmaxf(redm[0], redm[1]), fmaxf(redm[2], redm[3]));
  float lsum = 0.f;
#pragma unroll
  for (int j = 0; j < 16; ++j) {
    v[j] = __expf(v[j] - m);
    lsum += v[j];
  }
  lsum = wave_sum(lsum);
  if ((tid & 63) == 0) reds[tid >> 6] = lsum;
  __syncthreads();
  const float inv = 1.0f / (reds[0] + reds[1] + reds[2] + reds[3]);
  float* o = out + (size_t)s * L_DIM;
#pragma unroll
  for (int j = 0; j < 16; ++j) o[j * 256 + tid] = v[j] * inv;
}

// ---------------- attn_time ----------------
__global__ __launch_bounds__(256) void time_table_kernel(
    const int* __restrict__ his_t, const float* __restrict__ T,
    float* __restrict__ P) {
  __shared__ int cnt[NTIME];
  __shared__ float Ts[NTIME * NTIME];
  const int tid = threadIdx.x;
  if (tid < NTIME) cnt[tid] = 0;
  __syncthreads();
  for (int l = tid; l < L_DIM; l += 256) atomicAdd(&cnt[his_t[l]], 1);
  for (int i = tid; i < NTIME * NTIME; i += 256) Ts[i] = T[i];
  __syncthreads();
  if (tid < NTIME) {
    float m = -1e30f;
    for (int t = 0; t < NTIME; ++t) m = fmaxf(m, Ts[tid * NTIME + t]);
    float den = 0.f;
    for (int t = 0; t < NTIME; ++t)
      den += (float)cnt[t] * __expf(Ts[tid * NTIME + t] - m);
    const float inv = 1.0f / den;
    for (int t = 0; t < NTIME; ++t)
      P[tid * NTIME + t] = __expf(Ts[tid * NTIME + t] - m) * inv;
  }
}

__global__ __launch_bounds__(256) void time_out_kernel(
    const int* __restrict__ cur_t, const int* __restrict__ his_t,
    const float* __restrict__ P, float* __restrict__ out) {
  const int i = blockIdx.x * 256 + threadIdx.x;
  const int s = i >> 12;
  const int l = i & (L_DIM - 1);
  out[i] = P[cur_t[s] * NTIME + his_t[l]];
}

// ---------------- split: f32 -> tiled+swizzled hi/lo bf16 planes ----------
// Unified 6144-row space: rows 0..2047 = w1*user_emb, 2048..6143 = id_emb.
// Plane layout: tile (rb, ks, comp) of 8KB; rb=row>>7 in [0,48), ks in [0,16),
// comp 0=hi 1=lo. Within tile, element (rin, quad kq, e):
//   byte off = rin*64 + ((kq ^ ((rin>>1)&3)) * 16) + e*2   (bank XOR baked in)
// Also fuses bias[l] = w2 * dot(id_emb[l], soc): one wave == one row here.
__global__ __launch_bounds__(256) void split_kernel(
    const float* __restrict__ U, const float* __restrict__ Id,
    const float* __restrict__ w1p, const float* __restrict__ soc,
    const float* __restrict__ w2p, short* __restrict__ planes,
    float* __restrict__ bias) {
  const int chunk = blockIdx.x * 256 + threadIdx.x;
  const int row = chunk >> 6;  // 0..6143 (64 16B-chunks per row)
  const int lq = chunk & 63;   // k = lq*8 .. lq*8+7
  const bool isA = row < S_DIM;
  const float scale = isA ? w1p[0] : 1.0f;
  const float* src = isA ? (U + (size_t)row * D_DIM)
                         : (Id + (size_t)(row - S_DIM) * D_DIM);
  const int k0 = lq * 8;
  float dot = 0.f;
  short h[8], l[8];
#pragma unroll
  for (int e = 0; e < 8; ++e) {
    const int k = k0 + e;
    const float v = (k < D_DIM) ? src[k] : 0.0f;
    if (!isA && k < D_DIM) dot += v * soc[k];
    const float x = scale * v;
    const short hb = f2bf(x);
    h[e] = hb;
    l[e] = f2bf(x - bf2f(hb));
  }
  const int rb = row >> 7, rin = row & 127;
  const int ks = lq >> 2, kq = lq & 3;
  const int off = rin * 64 + ((kq ^ ((rin >> 1) & 3)) * 16);
  char* base = (char*)planes + ((size_t)(rb * 16 + ks) * 2) * 8192;
  *reinterpret_cast<int4*>(base + off) = *reinterpret_cast<const int4*>(h);
  *reinterpret_cast<int4*>(base + 8192 + off) =
      *reinterpret_cast<const int4*>(l);
  if (!isA) {
    const float d = wave_sum(dot);
    if ((threadIdx.x & 63) == 0) bias[row - S_DIM] = w2p[0] * d;
  }
}

// ---------------- split-bf16 MFMA GEMM (m97 structure) ----------------
// E = (w1*U).Id^T + bias via hi*hi + hi*lo + lo*hi, mfma_f32_32x32x16_bf16.
// 128x128 tile, BK=32, 4 waves (2x2, 64x64 each = 2x2 frags of 32x32).
// Staging: global_load_lds width=16 from the pre-tiled planes (linear copy).
__global__ __launch_bounds__(256, 2) void user_gemm_mfma(
    const short* __restrict__ planes, const float* __restrict__ bias,
    float* __restrict__ outE) {
  __shared__ __attribute__((aligned(1024))) char lds[32768];
  // LDS: Ahi @0, Alo @8192, Bhi @16384, Blo @24576
  const int tid = threadIdx.x;
  const int lane = tid & 63;
  const int wid = tid >> 6;
  const int wm = (wid >> 1) * 64;
  const int wn = (wid & 1) * 64;
  const int bm = blockIdx.y * 128;
  const int bn = blockIdx.x * 128;
  const int arb = blockIdx.y;         // A rowblock
  const int brb = 16 + blockIdx.x;    // B rowblock (B rows start at 2048)
  const char* gA = (const char*)planes + (size_t)arb * 16 * 2 * 8192;
  const char* gB = (const char*)planes + (size_t)brb * 16 * 2 * 8192;

  const int r32 = lane & 31;
  const int khl = lane >> 5;  // k-half within fragment

  f32x16 acc[2][2] = {};

  for (int ks = 0; ks < KPAD / 32; ++ks) {
    const char* tA = gA + (size_t)ks * 16384;
    const char* tB = gB + (size_t)ks * 16384;
#pragma unroll
    for (int q = 0; q < 4; ++q) {
      const int c = (q * 256 + tid) * 16;  // 0..16368
      __builtin_amdgcn_global_load_lds(
          (const __attribute__((address_space(1))) unsigned int*)(tA + c),
          (__attribute__((address_space(3))) unsigned int*)(lds + c), 16, 0, 0);
      __builtin_amdgcn_global_load_lds(
          (const __attribute__((address_space(1))) unsigned int*)(tB + c),
          (__attribute__((address_space(3))) unsigned int*)(lds + 16384 + c),
          16, 0, 0);
    }
    __syncthreads();
#pragma unroll
    for (int kf = 0; kf < 2; ++kf) {
      short8 ah[2], al[2], bh[2], bl[2];
#pragma unroll
      for (int i = 0; i < 2; ++i) {
        const int ra = wm + i * 32 + r32;
        const int rb_ = wn + i * 32 + r32;
        const int ga = ((kf * 2 + khl) ^ ((ra >> 1) & 3)) * 16;
        const int gb = ((kf * 2 + khl) ^ ((rb_ >> 1) & 3)) * 16;
        ah[i] = *reinterpret_cast<const short8*>(lds + ra * 64 + ga);
        al[i] = *reinterpret_cast<const short8*>(lds + 8192 + ra * 64 + ga);
        bh[i] = *reinterpret_cast<const short8*>(lds + 16384 + rb_ * 64 + gb);
        bl[i] = *reinterpret_cast<const short8*>(lds + 24576 + rb_ * 64 + gb);
      }
#pragma unroll
      for (int i = 0; i < 2; ++i)
#pragma unroll
        for (int j = 0; j < 2; ++j) {
          acc[i][j] = __builtin_amdgcn_mfma_f32_32x32x16_bf16(
              ah[i], bh[j], acc[i][j], 0, 0, 0);
          acc[i][j] = __builtin_amdgcn_mfma_f32_32x32x16_bf16(
              ah[i], bl[j], acc[i][j], 0, 0, 0);
          acc[i][j] = __builtin_amdgcn_mfma_f32_32x32x16_bf16(
              al[i], bh[j], acc[i][j], 0, 0, 0);
        }
    }
    __syncthreads();
  }

  // C/D layout (m74/m101): col=lane&31, row=(reg&3)+8*(reg>>2)+4*(lane>>5)
#pragma unroll
  for (int j = 0; j < 2; ++j) {
    const int col = bn + wn + j * 32 + r32;
    const float bj = bias[col];
#pragma unroll
    for (int i = 0; i < 2; ++i) {
      const int rbase = bm + wm + i * 32 + 4 * khl;
#pragma unroll
      for (int reg = 0; reg < 16; ++reg) {
        const int rowm = rbase + (reg & 3) + 8 * (reg >> 2);
        outE[(size_t)rowm * L_DIM + col] = acc[i][j][reg] + bj;
      }
    }
  }
}

// in-place row softmax of the user plane
__global__ __launch_bounds__(256) void user_softmax_kernel(
    float* __restrict__ outE) {
  __shared__ float redm[4];
  __shared__ float reds[4];
  const int s = blockIdx.x;
  const int tid = threadIdx.x;
  float* row = outE + (size_t)s * L_DIM;
  float4 v[4];
  float lmax = -1e30f;
#pragma unroll
  for (int j = 0; j < 4; ++j) {
    v[j] = *reinterpret_cast<const float4*>(&row[(j * 256 + tid) * 4]);
    lmax = fmaxf(lmax, fmaxf(fmaxf(v[j].x, v[j].y), fmaxf(v[j].z, v[j].w)));
  }
  lmax = wave_max(lmax);
  if ((tid & 63) == 0) redm[tid >> 6] = lmax;
  __syncthreads();
  const float m = fmaxf(fmaxf(redm[0], redm[1]), fmaxf(redm[2], redm[3]));
  float lsum = 0.f;
#pragma unroll
  for (int j = 0; j < 4; ++j) {
    v[j].x = __expf(v[j].x - m);
    v[j].y = __expf(v[j].y - m);
    v[j].z = __expf(v[j].z - m);
    v[j].w = __expf(v[j].w - m);
    lsum += v[j].x + v[j].y + v[j].z + v[j].w;
  }
  lsum = wave_sum(lsum);
  if ((tid & 63) == 0) reds[tid >> 6] = lsum;
  __syncthreads();
  const float inv = 1.0f / (reds[0] + reds[1] + reds[2] + reds[3]);
#pragma unroll
  for (int j = 0; j < 4; ++j) {
    v[j].x *= inv;
    v[j].y *= inv;
    v[j].z *= inv;
    v[j].w *= inv;
    *reinterpret_cast<float4*>(&row[(j * 256 + tid) * 4]) = v[j];
  }
}

extern "C" void kernel_launch(void* const* d_in, const int* in_sizes, int n_in,
                              void* d_out, int out_size, void* d_ws,
                              size_t ws_size, hipStream_t stream) {
  const int* his = (const int*)d_in[0];
  const int* cur = (const int*)d_in[1];
  const int* his_t = (const int*)d_in[2];
  const int* cur_t = (const int*)d_in[3];
  const float* poi = (const float*)d_in[4];
  const float* tsim = (const float*)d_in[5];
  const float* uemb = (const float*)d_in[6];
  const float* idemb = (const float*)d_in[7];
  const float* soc = (const float*)d_in[8];
  const float* w1 = (const float*)d_in[9];
  const float* w2 = (const float*)d_in[10];

  float* out = (float*)d_out;
  float* out_loc = out;
  float* out_time = out + (size_t)S_DIM * L_DIM;
  float* out_user = out + 2 * (size_t)S_DIM * L_DIM;

  // planes: 48 rowblocks x 16 ksteps x 2 comps x 8KB = 12.58 MB
  const size_t plane_bytes = (size_t)48 * 16 * 2 * 8192;
  short* planes;
  float* bias;
  float* P;
  if (ws_size >= plane_bytes + 32768) {
    planes = (short*)d_ws;
    bias = (float*)((char*)d_ws + plane_bytes);
    P = bias + L_DIM;
  } else {
    // fallback: stash planes in the attn_loc output plane (33.5 MB),
    // which is only written by attn_loc_kernel at the very end.
    planes = (short*)out_loc;
    bias = (float*)d_ws;
    P = bias + L_DIM;
  }

  hipLaunchKernelGGL(split_kernel, dim3((S_DIM + L_DIM) * 64 / 256), dim3(256),
                     0, stream, uemb, idemb, w1, soc, w2, planes, bias);
  hipLaunchKernelGGL(user_gemm_mfma, dim3(L_DIM / 128, S_DIM / 128), dim3(256),
                     0, stream, planes, bias, out_user);
  hipLaunchKernelGGL(user_softmax_kernel, dim3(S_DIM), dim3(256), 0, stream,
                     out_user);
  hipLaunchKernelGGL(time_table_kernel, dim3(1), dim3(256), 0, stream, his_t,
                     tsim, P);
  hipLaunchKernelGGL(time_out_kernel, dim3((S_DIM * L_DIM) / 256), dim3(256),
                     0, stream, cur_t, his_t, P, out_time);
  hipLaunchKernelGGL(attn_loc_kernel, dim3(S_DIM), dim3(256), 0, stream, cur,
                     his, poi, out_loc);
}

// Round 5
// 88.593 us; speedup vs baseline: 2.0809x; 1.1748x over previous
//
#include <hip/hip_runtime.h>
#include <math.h>

#define S_DIM 2048
#define L_DIM 4096
#define D_DIM 500
#define KPAD 512
#define NPOI 10000
#define NTIME 48

typedef __attribute__((ext_vector_type(8))) short short8;
typedef __attribute__((ext_vector_type(16))) float f32x16;

#define A_BYTES 4194304            // 8 mb x 16 ks x 32768
#define PLANE_BYTES 12582912       // A (4 MB) + B (32 nb x 16 ks x 16384)
#define LDSBUF 49152               // [Ahi 16K | Alo 16K | Bhi 8K | Blo 8K]

// ---------------- helpers ----------------
__device__ __forceinline__ float wave_max(float v) {
#pragma unroll
  for (int o = 32; o > 0; o >>= 1) v = fmaxf(v, __shfl_down(v, o, 64));
  return v;
}
__device__ __forceinline__ float wave_sum(float v) {
#pragma unroll
  for (int o = 32; o > 0; o >>= 1) v += __shfl_down(v, o, 64);
  return v;
}
__device__ __forceinline__ short f2bf(float x) {  // RNE f32 -> bf16 bits
  union { float f; unsigned u; } v;
  v.f = x;
  const unsigned r = v.u + 0x7fffu + ((v.u >> 16) & 1u);
  return (short)(r >> 16);
}
__device__ __forceinline__ float bf2f(short h) {
  union { unsigned u; float f; } v;
  v.u = ((unsigned)(unsigned short)h) << 16;
  return v.f;
}

// ------- attn_loc + attn_time planes (merged): LDS row stage + gathers -----
__global__ __launch_bounds__(256) void attn_loc_time_kernel(
    const int* __restrict__ cur, const int* __restrict__ his,
    const float* __restrict__ poi, const int* __restrict__ cur_t,
    const int* __restrict__ his_t, const float* __restrict__ P,
    float* __restrict__ out_loc, float* __restrict__ out_time) {
  __shared__ __attribute__((aligned(16))) float rowbuf[NPOI];
  __shared__ float Prow[NTIME];
  __shared__ float redm[4];
  __shared__ float reds[4];
  const int s = blockIdx.x;
  const int tid = threadIdx.x;
  if (tid < NTIME) Prow[tid] = P[cur_t[s] * NTIME + tid];
  const float* row = poi + (size_t)cur[s] * NPOI;  // 40000B-aligned
  for (int i = tid; i < NPOI / 4; i += 256)
    *reinterpret_cast<float4*>(&rowbuf[i * 4]) =
        *reinterpret_cast<const float4*>(row + i * 4);
  __syncthreads();
  float v[16];
  float lmax = -1e30f;
#pragma unroll
  for (int j = 0; j < 16; ++j) {
    const int l = j * 256 + tid;
    const float d = rowbuf[his[l]];
    const float e = (d != 0.0f) ? (1.0f / d) : 1e-6f;
    v[j] = e;
    lmax = fmaxf(lmax, e);
  }
  lmax = wave_max(lmax);
  if ((tid & 63) == 0) redm[tid >> 6] = lmax;
  __syncthreads();
  const float m = fmaxf(fmaxf(redm[0], redm[1]), fmaxf(redm[2], redm[3]));
  float lsum = 0.f;
#pragma unroll
  for (int j = 0; j < 16; ++j) {
    v[j] = __expf(v[j] - m);
    lsum += v[j];
  }
  lsum = wave_sum(lsum);
  if ((tid & 63) == 0) reds[tid >> 6] = lsum;
  __syncthreads();
  const float inv = 1.0f / (reds[0] + reds[1] + reds[2] + reds[3]);
  float* ol = out_loc + (size_t)s * L_DIM;
  float* ot = out_time + (size_t)s * L_DIM;
#pragma unroll
  for (int j = 0; j < 16; ++j) {
    const int l = j * 256 + tid;
    ol[l] = v[j] * inv;
    ot[l] = Prow[his_t[l]];
  }
}

// ---------------- attn_time 48x48 table ----------------
__global__ __launch_bounds__(256) void time_table_kernel(
    const int* __restrict__ his_t, const float* __restrict__ T,
    float* __restrict__ P) {
  __shared__ int cnt[NTIME];
  __shared__ float Ts[NTIME * NTIME];
  const int tid = threadIdx.x;
  if (tid < NTIME) cnt[tid] = 0;
  __syncthreads();
  for (int l = tid; l < L_DIM; l += 256) atomicAdd(&cnt[his_t[l]], 1);
  for (int i = tid; i < NTIME * NTIME; i += 256) Ts[i] = T[i];
  __syncthreads();
  if (tid < NTIME) {
    float m = -1e30f;
    for (int t = 0; t < NTIME; ++t) m = fmaxf(m, Ts[tid * NTIME + t]);
    float den = 0.f;
    for (int t = 0; t < NTIME; ++t)
      den += (float)cnt[t] * __expf(Ts[tid * NTIME + t] - m);
    const float inv = 1.0f / den;
    for (int t = 0; t < NTIME; ++t)
      P[tid * NTIME + t] = __expf(Ts[tid * NTIME + t] - m) * inv;
  }
}

// ------- split: f32 -> GEMM-tiled, bank-swizzled hi/lo bf16 planes --------
// A (rows 0..2047 = w1*user_emb): tile (mb=row>>8, ks=k>>5) of 32KB
//   [hi 16K | lo 16K]; within: rin=row&255, granule g=(k>>3)&3 (16B = 8 bf16),
//   swizzled g' = g ^ (rin&3) ^ ((rin>>2)&3); off = rin*64 + g'*16.
// B (rows 2048.. = id_emb): tile (nb, ks) of 16KB [hi 8K | lo 8K], rin&127.
// Swizzle breaks the ds_read_b128 bank collision to 2-way (free, m136).
// Fuses bias[l] = w2 * dot(id_emb[l], soc): one wave == one row.
__global__ __launch_bounds__(256) void split_kernel(
    const float* __restrict__ U, const float* __restrict__ Id,
    const float* __restrict__ w1p, const float* __restrict__ soc,
    const float* __restrict__ w2p, short* __restrict__ planes,
    float* __restrict__ bias) {
  const int chunk = blockIdx.x * 256 + threadIdx.x;
  const int row = chunk >> 6;  // 0..6143
  const int lq = chunk & 63;   // 8-elem granule index along K
  const bool isA = row < S_DIM;
  const float scale = isA ? w1p[0] : 1.0f;
  const float* src = isA ? (U + (size_t)row * D_DIM)
                         : (Id + (size_t)(row - S_DIM) * D_DIM);
  const int k0 = lq * 8;
  float dot = 0.f;
  short h[8], l[8];
#pragma unroll
  for (int e = 0; e < 8; ++e) {
    const int k = k0 + e;
    const float v = (k < D_DIM) ? src[k] : 0.0f;
    if (!isA && k < D_DIM) dot += v * soc[k];
    const float x = scale * v;
    const short hb = f2bf(x);
    h[e] = hb;
    l[e] = f2bf(x - bf2f(hb));
  }
  const int ks = lq >> 2, g = lq & 3;
  if (isA) {
    const int mb = row >> 8, rin = row & 255;
    const int gs = g ^ (rin & 3) ^ ((rin >> 2) & 3);
    char* base = (char*)planes + (size_t)(mb * 16 + ks) * 32768 + rin * 64 +
                 gs * 16;
    *reinterpret_cast<int4*>(base) = *reinterpret_cast<const int4*>(h);
    *reinterpret_cast<int4*>(base + 16384) = *reinterpret_cast<const int4*>(l);
  } else {
    const int rb = row - S_DIM;
    const int nb = rb >> 7, rin = rb & 127;
    const int gs = g ^ (rin & 3) ^ ((rin >> 2) & 3);
    char* base = (char*)planes + A_BYTES + (size_t)(nb * 16 + ks) * 16384 +
                 rin * 64 + gs * 16;
    *reinterpret_cast<int4*>(base) = *reinterpret_cast<const int4*>(h);
    *reinterpret_cast<int4*>(base + 8192) = *reinterpret_cast<const int4*>(l);
    const float d = wave_sum(dot);
    if ((threadIdx.x & 63) == 0) bias[rb] = w2p[0] * d;
  }
}

// ---------------- split-bf16 MFMA GEMM, 256x128 tile, 1 block/CU ----------
// E = (w1*U).Id^T + bias via hi*hi + hi*lo + lo*hi, mfma_f32_32x32x16_bf16.
// 512 thr = 8 waves (4m x 2n), 64x64 per wave. BK=32, dbuf LDS (96KB),
// 2-phase prefetch: STAGE(next) -> compute(cur) -> one __syncthreads.
__global__ __launch_bounds__(512, 2) void user_gemm_mfma(
    const short* __restrict__ planes, const float* __restrict__ bias,
    float* __restrict__ outE) {
  __shared__ __attribute__((aligned(1024))) char lds[2 * LDSBUF];
  const int tid = threadIdx.x;
  const int lane = tid & 63;
  const int wid = tid >> 6;
  // bijective XCD swizzle: 256 blocks = 8 XCDs x 32; n-strip chunks so each
  // XCD's L2 working set = 4-n-tile B strip (1.05MB) + A plane (4.2MB).
  const int ob = (blockIdx.x & 7) * 32 + (blockIdx.x >> 3);
  const int nb = ob >> 3;  // 0..31
  const int mb = ob & 7;   // 0..7
  const int bm = mb * 256, bn = nb * 128;
  const char* gA = (const char*)planes + (size_t)mb * 16 * 32768;
  const char* gB = (const char*)planes + A_BYTES + (size_t)nb * 16 * 16384;
  const int wm = (wid >> 1) * 64;
  const int wn = (wid & 1) * 64;
  const int r32 = lane & 31;
  const int khl = lane >> 5;

  f32x16 acc[2][2] = {};

#define STAGE(ks_, buf_)                                                      \
  {                                                                           \
    const int _ks = (ks_);                                                    \
    char* _dst = lds + (buf_)*LDSBUF;                                         \
    _Pragma("unroll") for (int q = 0; q < 6; ++q) {                           \
      const int off = (q * 512 + tid) * 16;                                   \
      if (q < 4) {                                                            \
        __builtin_amdgcn_global_load_lds(                                     \
            (const __attribute__((address_space(1))) unsigned*)(gA +          \
                (size_t)_ks * 32768 + off),                                   \
            (__attribute__((address_space(3))) unsigned*)(_dst + off), 16, 0, \
            0);                                                               \
      } else {                                                                \
        __builtin_amdgcn_global_load_lds(                                     \
            (const __attribute__((address_space(1))) unsigned*)(gB +          \
                (size_t)_ks * 16384 + (off - 32768)),                         \
            (__attribute__((address_space(3))) unsigned*)(_dst + off), 16, 0, \
            0);                                                               \
      }                                                                       \
    }                                                                         \
  }

  STAGE(0, 0);
  __syncthreads();
  int buf = 0;
  for (int ks = 0; ks < 16; ++ks) {
    if (ks < 15) STAGE(ks + 1, buf ^ 1);
    const char* La = lds + buf * LDSBUF;
    const char* Lb = La + 32768;
#pragma unroll
    for (int s16 = 0; s16 < 2; ++s16) {
      short8 ah[2], al[2], bh[2], bl[2];
#pragma unroll
      for (int i = 0; i < 2; ++i) {
        const int ra = wm + i * 32 + r32;
        const int ga = ((s16 * 2 + khl) ^ (ra & 3) ^ ((ra >> 2) & 3)) * 16;
        ah[i] = *reinterpret_cast<const short8*>(La + ra * 64 + ga);
        al[i] = *reinterpret_cast<const short8*>(La + 16384 + ra * 64 + ga);
        const int rbb = wn + i * 32 + r32;
        const int gb = ((s16 * 2 + khl) ^ (rbb & 3) ^ ((rbb >> 2) & 3)) * 16;
        bh[i] = *reinterpret_cast<const short8*>(Lb + rbb * 64 + gb);
        bl[i] = *reinterpret_cast<const short8*>(Lb + 8192 + rbb * 64 + gb);
      }
#pragma unroll
      for (int i = 0; i < 2; ++i)
#pragma unroll
        for (int j = 0; j < 2; ++j) {
          acc[i][j] = __builtin_amdgcn_mfma_f32_32x32x16_bf16(
              ah[i], bh[j], acc[i][j], 0, 0, 0);
          acc[i][j] = __builtin_amdgcn_mfma_f32_32x32x16_bf16(
              ah[i], bl[j], acc[i][j], 0, 0, 0);
          acc[i][j] = __builtin_amdgcn_mfma_f32_32x32x16_bf16(
              al[i], bh[j], acc[i][j], 0, 0, 0);
        }
    }
    __syncthreads();
    buf ^= 1;
  }
#undef STAGE

  // C/D layout (m74/m101, r3-validated): col=lane&31,
  // row=(reg&3)+8*(reg>>2)+4*(lane>>5)
  const int rg = 4 * khl;
#pragma unroll
  for (int j = 0; j < 2; ++j) {
    const int col = bn + wn + j * 32 + r32;
    const float bj = bias[col];
#pragma unroll
    for (int i = 0; i < 2; ++i) {
      const int rbase = bm + wm + i * 32 + rg;
#pragma unroll
      for (int reg = 0; reg < 16; ++reg) {
        const int rowm = rbase + (reg & 3) + 8 * (reg >> 2);
        outE[(size_t)rowm * L_DIM + col] = acc[i][j][reg] + bj;
      }
    }
  }
}

// in-place row softmax of the user plane
__global__ __launch_bounds__(256) void user_softmax_kernel(
    float* __restrict__ outE) {
  __shared__ float redm[4];
  __shared__ float reds[4];
  const int s = blockIdx.x;
  const int tid = threadIdx.x;
  float* row = outE + (size_t)s * L_DIM;
  float4 v[4];
  float lmax = -1e30f;
#pragma unroll
  for (int j = 0; j < 4; ++j) {
    v[j] = *reinterpret_cast<const float4*>(&row[(j * 256 + tid) * 4]);
    lmax = fmaxf(lmax, fmaxf(fmaxf(v[j].x, v[j].y), fmaxf(v[j].z, v[j].w)));
  }
  lmax = wave_max(lmax);
  if ((tid & 63) == 0) redm[tid >> 6] = lmax;
  __syncthreads();
  const float m = fmaxf(fmaxf(redm[0], redm[1]), fmaxf(redm[2], redm[3]));
  float lsum = 0.f;
#pragma unroll
  for (int j = 0; j < 4; ++j) {
    v[j].x = __expf(v[j].x - m);
    v[j].y = __expf(v[j].y - m);
    v[j].z = __expf(v[j].z - m);
    v[j].w = __expf(v[j].w - m);
    lsum += v[j].x + v[j].y + v[j].z + v[j].w;
  }
  lsum = wave_sum(lsum);
  if ((tid & 63) == 0) reds[tid >> 6] = lsum;
  __syncthreads();
  const float inv = 1.0f / (reds[0] + reds[1] + reds[2] + reds[3]);
#pragma unroll
  for (int j = 0; j < 4; ++j) {
    v[j].x *= inv;
    v[j].y *= inv;
    v[j].z *= inv;
    v[j].w *= inv;
    *reinterpret_cast<float4*>(&row[(j * 256 + tid) * 4]) = v[j];
  }
}

extern "C" void kernel_launch(void* const* d_in, const int* in_sizes, int n_in,
                              void* d_out, int out_size, void* d_ws,
                              size_t ws_size, hipStream_t stream) {
  const int* his = (const int*)d_in[0];
  const int* cur = (const int*)d_in[1];
  const int* his_t = (const int*)d_in[2];
  const int* cur_t = (const int*)d_in[3];
  const float* poi = (const float*)d_in[4];
  const float* tsim = (const float*)d_in[5];
  const float* uemb = (const float*)d_in[6];
  const float* idemb = (const float*)d_in[7];
  const float* soc = (const float*)d_in[8];
  const float* w1 = (const float*)d_in[9];
  const float* w2 = (const float*)d_in[10];

  float* out = (float*)d_out;
  float* out_loc = out;
  float* out_time = out + (size_t)S_DIM * L_DIM;
  float* out_user = out + 2 * (size_t)S_DIM * L_DIM;

  short* planes;
  float* bias;
  float* P;
  if (ws_size >= (size_t)PLANE_BYTES + 32768) {
    planes = (short*)d_ws;
    bias = (float*)((char*)d_ws + PLANE_BYTES);
    P = bias + L_DIM;
  } else {
    // fallback: stash planes in the attn_loc output plane (33.5 MB),
    // which is only written by the final kernel.
    planes = (short*)out_loc;
    bias = (float*)d_ws;
    P = bias + L_DIM;
  }

  hipLaunchKernelGGL(split_kernel, dim3((S_DIM + L_DIM) * 64 / 256), dim3(256),
                     0, stream, uemb, idemb, w1, soc, w2, planes, bias);
  hipLaunchKernelGGL(time_table_kernel, dim3(1), dim3(256), 0, stream, his_t,
                     tsim, P);
  hipLaunchKernelGGL(user_gemm_mfma, dim3(256), dim3(512), 0, stream, planes,
                     bias, out_user);
  hipLaunchKernelGGL(user_softmax_kernel, dim3(S_DIM), dim3(256), 0, stream,
                     out_user);
  hipLaunchKernelGGL(attn_loc_time_kernel, dim3(S_DIM), dim3(256), 0, stream,
                     cur, his, poi, cur_t, his_t, P, out_loc, out_time);
}